// Round 1
// baseline (578.988 us; speedup 1.0000x reference)
//
#include <hip/hip_runtime.h>
#include <hip/hip_bf16.h>

#define B_ROWS 65536
#define KNUM 20

// ---------------------------------------------------------------------------
// Kernel 1: gather + masked-mean + concat -> X[B, 448]
// One wave (64 lanes) per row. All loads coalesced (lane = dim).
// ---------------------------------------------------------------------------
__global__ __launch_bounds__(256) void gather_concat(
    const int* __restrict__ user, const int* __restrict__ item,
    const int* __restrict__ pk, const int* __restrict__ tk, const int* __restrict__ ik,
    const int* __restrict__ vp, const int* __restrict__ vt, const int* __restrict__ vi,
    const float* __restrict__ eu, const float* __restrict__ ei,
    const float* __restrict__ ek,
    float* __restrict__ X)
{
    const int tid  = threadIdx.x;
    const int lane = tid & 63;
    const int row  = blockIdx.x * 4 + (tid >> 6);

    float* xr = X + (size_t)row * 448;

    const int u  = user[row];
    const int it = item[row];
    xr[lane]        = eu[(size_t)u  * 128 + lane];
    xr[64  + lane]  = eu[(size_t)u  * 128 + 64 + lane];
    xr[128 + lane]  = ei[(size_t)it * 128 + lane];
    xr[192 + lane]  = ei[(size_t)it * 128 + 64 + lane];

    // masked means over emb_k (valid is wave-uniform -> no divergence)
    {
        const int valid = vp[row];
        float acc = 0.f;
        for (int j = 0; j < valid; ++j) {
            const int kk = pk[row * KNUM + j];
            acc += ek[(size_t)kk * 64 + lane];
        }
        xr[256 + lane] = (valid > 0) ? acc / (float)valid : 0.f;
    }
    {
        const int valid = vt[row];
        float acc = 0.f;
        for (int j = 0; j < valid; ++j) {
            const int kk = tk[row * KNUM + j];
            acc += ek[(size_t)kk * 64 + lane];
        }
        xr[320 + lane] = (valid > 0) ? acc / (float)valid : 0.f;
    }
    {
        const int valid = vi[row];
        float acc = 0.f;
        for (int j = 0; j < valid; ++j) {
            const int kk = ik[row * KNUM + j];
            acc += ek[(size_t)kk * 64 + lane];
        }
        xr[384 + lane] = (valid > 0) ? acc / (float)valid : 0.f;
    }
}

// ---------------------------------------------------------------------------
// Templated fp32 SGEMM: C[M,N] = act(A[M,K] @ W[K,N] + bias)
// BM=128, KB=16, 256 threads. TN/BN chosen per layer.
// ---------------------------------------------------------------------------
template<int K, int N, int BN, int TN, bool RELU>
__global__ __launch_bounds__(256) void gemm_bias_act(
    const float* __restrict__ A, const float* __restrict__ W,
    const float* __restrict__ bias, float* __restrict__ C)
{
    constexpr int BM = 128;
    constexpr int KB = 16;
    constexpr int TM = 8;
    constexpr int TX = BN / TN;                 // threads along n
    static_assert(TX * (BM / TM) == 256, "block mapping");

    __shared__ float As[KB][BM];                // k-major: read addr uniform in k
    __shared__ float Bs[KB][BN];

    const int tid = threadIdx.x;
    const int tx  = tid % TX;
    const int ty  = tid / TX;
    const int m0  = blockIdx.y * BM;
    const int n0  = blockIdx.x * BN;

    float acc[TM][TN] = {};

    const int la_m = tid >> 1;                  // 0..127
    const int la_k = (tid & 1) * 8;             // 0 or 8

    for (int k0 = 0; k0 < K; k0 += KB) {
        // stage A tile (transposed into LDS)
        const float* ap = A + (size_t)(m0 + la_m) * K + k0 + la_k;
        float4 a0 = *(const float4*)ap;
        float4 a1 = *(const float4*)(ap + 4);
        As[la_k + 0][la_m] = a0.x; As[la_k + 1][la_m] = a0.y;
        As[la_k + 2][la_m] = a0.z; As[la_k + 3][la_m] = a0.w;
        As[la_k + 4][la_m] = a1.x; As[la_k + 5][la_m] = a1.y;
        As[la_k + 6][la_m] = a1.z; As[la_k + 7][la_m] = a1.w;

        // stage W tile
        #pragma unroll
        for (int i = tid * 4; i < KB * BN; i += 256 * 4) {
            const int bk = i / BN;
            const int bn = i % BN;
            *(float4*)&Bs[bk][bn] = *(const float4*)(W + (size_t)(k0 + bk) * N + n0 + bn);
        }
        __syncthreads();

        #pragma unroll
        for (int k = 0; k < KB; ++k) {
            float a[TM], b[TN];
            #pragma unroll
            for (int i = 0; i < TM; i += 4)
                *(float4*)&a[i] = *(const float4*)&As[k][ty * TM + i];
            #pragma unroll
            for (int j = 0; j < TN; j += 4)
                *(float4*)&b[j] = *(const float4*)&Bs[k][tx * TN + j];
            #pragma unroll
            for (int i = 0; i < TM; ++i)
                #pragma unroll
                for (int j = 0; j < TN; ++j)
                    acc[i][j] = fmaf(a[i], b[j], acc[i][j]);
        }
        __syncthreads();
    }

    // epilogue: bias + optional relu, vectorized store
    #pragma unroll
    for (int i = 0; i < TM; ++i) {
        const size_t m = (size_t)(m0 + ty * TM + i);
        #pragma unroll
        for (int j = 0; j < TN; j += 4) {
            const int n = n0 + tx * TN + j;
            float4 r;
            r.x = acc[i][j + 0] + bias[n + 0];
            r.y = acc[i][j + 1] + bias[n + 1];
            r.z = acc[i][j + 2] + bias[n + 2];
            r.w = acc[i][j + 3] + bias[n + 3];
            if (RELU) {
                r.x = fmaxf(r.x, 0.f); r.y = fmaxf(r.y, 0.f);
                r.z = fmaxf(r.z, 0.f); r.w = fmaxf(r.w, 0.f);
            }
            *(float4*)&C[m * N + n] = r;
        }
    }
}

// ---------------------------------------------------------------------------
// Kernel 5: out[r] = H3[r,:] . Wp + bp   (H3: [B,64], Wp: [64])
// ---------------------------------------------------------------------------
__global__ __launch_bounds__(256) void final_dot(
    const float* __restrict__ H, const float* __restrict__ Wp,
    const float* __restrict__ bp, float* __restrict__ out)
{
    __shared__ float w[64];
    const int tid = threadIdx.x;
    if (tid < 64) w[tid] = Wp[tid];
    __syncthreads();

    const int r = blockIdx.x * blockDim.x + tid;
    const float4* h = (const float4*)(H + (size_t)r * 64);
    float acc = 0.f;
    #pragma unroll
    for (int i = 0; i < 16; ++i) {
        float4 v = h[i];
        acc = fmaf(v.x, w[4 * i + 0], acc);
        acc = fmaf(v.y, w[4 * i + 1], acc);
        acc = fmaf(v.z, w[4 * i + 2], acc);
        acc = fmaf(v.w, w[4 * i + 3], acc);
    }
    out[r] = acc + bp[0];
}

// ---------------------------------------------------------------------------
extern "C" void kernel_launch(void* const* d_in, const int* in_sizes, int n_in,
                              void* d_out, int out_size, void* d_ws, size_t ws_size,
                              hipStream_t stream) {
    (void)in_sizes; (void)n_in; (void)out_size; (void)ws_size;

    const int*   user = (const int*)d_in[0];
    const int*   item = (const int*)d_in[1];
    const int*   pk   = (const int*)d_in[2];
    const int*   tk   = (const int*)d_in[3];
    const int*   ik   = (const int*)d_in[4];
    const int*   vp   = (const int*)d_in[5];
    const int*   vt   = (const int*)d_in[6];
    const int*   vi   = (const int*)d_in[7];
    const float* eu   = (const float*)d_in[8];
    const float* ei   = (const float*)d_in[9];
    const float* ek   = (const float*)d_in[10];
    const float* W1   = (const float*)d_in[11];
    const float* b1   = (const float*)d_in[12];
    const float* W2   = (const float*)d_in[13];
    const float* b2   = (const float*)d_in[14];
    const float* W3   = (const float*)d_in[15];
    const float* b3   = (const float*)d_in[16];
    const float* Wp   = (const float*)d_in[17];
    const float* bp   = (const float*)d_in[18];
    float* out = (float*)d_out;

    // workspace layout (X dead after GEMM1 -> H2 aliases X; H1 dead after
    // GEMM2 -> H3 aliases H1). Peak = (448+256)*B*4 = 184.5 MB.
    float* X  = (float*)d_ws;
    float* H1 = X + (size_t)B_ROWS * 448;
    float* H2 = X;
    float* H3 = H1;

    gather_concat<<<B_ROWS / 4, 256, 0, stream>>>(
        user, item, pk, tk, ik, vp, vt, vi, eu, ei, ek, X);

    // layer 1: [B,448] @ [448,256] + b1, relu
    gemm_bias_act<448, 256, 128, 8, true>
        <<<dim3(256 / 128, B_ROWS / 128), 256, 0, stream>>>(X, W1, b1, H1);

    // layer 2: [B,256] @ [256,128] + b2, relu
    gemm_bias_act<256, 128, 128, 8, true>
        <<<dim3(1, B_ROWS / 128), 256, 0, stream>>>(H1, W2, b2, H2);

    // layer 3: [B,128] @ [128,64] + b3, relu
    gemm_bias_act<128, 64, 64, 4, true>
        <<<dim3(1, B_ROWS / 128), 256, 0, stream>>>(H2, W3, b3, H3);

    // final: [B,64] @ [64,1] + bp
    final_dot<<<B_ROWS / 256, 256, 0, stream>>>(H3, Wp, bp, out);
}

// Round 3
// 323.957 us; speedup vs baseline: 1.7872x; 1.7872x over previous
//
#include <hip/hip_runtime.h>
#include <hip/hip_bf16.h>

#define B_ROWS 65536
#define KNUM 20

typedef short  bfrag8 __attribute__((ext_vector_type(8)));  // 8 bf16 (4 VGPRs)
typedef float  facc4  __attribute__((ext_vector_type(4)));  // 4 fp32 acc

__device__ __forceinline__ unsigned short f2bf(float f) {
    union { float f; unsigned u; } x; x.f = f;
    unsigned r = (x.u + 0x7FFFu + ((x.u >> 16) & 1u)) >> 16;   // RNE
    return (unsigned short)r;
}
__device__ __forceinline__ float bf2f(unsigned s) {
    union { unsigned u; float f; } x; x.u = s << 16; return x.f;
}

// ---------------------------------------------------------------------------
// Kernel 1: gather + masked-mean + concat -> X[B, 448] bf16
// One wave per row. K-loops fully unrolled & predicated: all 20 gather loads
// are independent (no idx->load dependent chain), mask via cndmask.
// ---------------------------------------------------------------------------
__global__ __launch_bounds__(256) void gather_concat(
    const int* __restrict__ user, const int* __restrict__ item,
    const int* __restrict__ pk, const int* __restrict__ tk, const int* __restrict__ ik,
    const int* __restrict__ vp, const int* __restrict__ vt, const int* __restrict__ vi,
    const float* __restrict__ eu, const float* __restrict__ ei,
    const float* __restrict__ ek,
    unsigned short* __restrict__ X)
{
    const int tid  = threadIdx.x;
    const int lane = tid & 63;
    const int row  = blockIdx.x * 4 + (tid >> 6);

    unsigned short* xr = X + (size_t)row * 448;

    const int u  = user[row];
    const int it = item[row];
    float2 a = *(const float2*)(eu + (size_t)u  * 128 + 2 * lane);
    float2 b = *(const float2*)(ei + (size_t)it * 128 + 2 * lane);
    ushort2 pa; pa.x = f2bf(a.x); pa.y = f2bf(a.y);
    ushort2 pb; pb.x = f2bf(b.x); pb.y = f2bf(b.y);
    *(ushort2*)(xr + 2 * lane)       = pa;
    *(ushort2*)(xr + 128 + 2 * lane) = pb;

    const int* idx[3] = { pk + row * KNUM, tk + row * KNUM, ik + row * KNUM };
    const int  val[3] = { vp[row], vt[row], vi[row] };

    #pragma unroll
    for (int s = 0; s < 3; ++s) {
        const int valid = val[s];
        float acc = 0.f;
        #pragma unroll
        for (int j = 0; j < KNUM; ++j) {
            const int kk = idx[s][j];                       // always in-bounds
            const float v = ek[(size_t)kk * 64 + lane];     // 256B coalesced, L2-hot
            acc += (j < valid) ? v : 0.f;
        }
        const float m = (valid > 0) ? acc / (float)valid : 0.f;
        xr[256 + 64 * s + lane] = f2bf(m);
    }
}

// ---------------------------------------------------------------------------
// MFMA bf16 GEMM: C[M,N] = bf16(relu(A[M,K] @ W[K,N] + bias))
// A row-major bf16, W row-major fp32 (converted during LDS staging, stored
// transposed so B-fragment loads mirror A-fragment loads).
// BM=128, BK=64, 256 threads = 4 waves in 2x2; wave tile 64 x BN/2 via
// 4 x NT grid of 16x16x32 MFMAs.
// LDS row stride = BK+8 ushorts (144 B = 9*16 B): keeps b128 alignment and
// spreads the 16B-chunk start banks across all 8 start groups (uniform).
// ---------------------------------------------------------------------------
template<int K, int N, int BN>
__global__ __launch_bounds__(256, 2) void gemm_mfma(
    const unsigned short* __restrict__ A, const float* __restrict__ W,
    const float* __restrict__ bias, unsigned short* __restrict__ C)
{
    constexpr int BM  = 128;
    constexpr int BK  = 64;
    constexpr int STR = BK + 8;            // 72 ushorts per row
    constexpr int NT  = BN / 32;           // n-tiles per wave

    __shared__ unsigned short As[BM * STR];
    __shared__ unsigned short Ws[BN * STR];

    const int tid  = threadIdx.x;
    const int lane = tid & 63;
    const int wid  = tid >> 6;
    const int wm   = wid & 1;
    const int wn   = wid >> 1;
    const int lm   = lane & 15;
    const int quad = lane >> 4;
    const int m0   = blockIdx.y * BM;
    const int n0   = blockIdx.x * BN;

    facc4 acc[4][NT];
    #pragma unroll
    for (int mt = 0; mt < 4; ++mt)
        #pragma unroll
        for (int nt = 0; nt < NT; ++nt)
            acc[mt][nt] = (facc4){0.f, 0.f, 0.f, 0.f};

    for (int k0 = 0; k0 < K; k0 += BK) {
        // ---- stage A tile: BM x BK bf16 (8192 ushorts, 32/thread, b128 I/O)
        #pragma unroll
        for (int i = 0; i < (BM * BK) / (256 * 8); ++i) {
            const int idx = tid * 8 + i * 2048;
            const int r = idx / BK, kk = idx % BK;
            bfrag8 v = *(const bfrag8*)(A + (size_t)(m0 + r) * K + k0 + kk);
            *(bfrag8*)(As + r * STR + kk) = v;
        }
        // ---- stage W tile transposed: W[k0..+BK][n0..+BN] fp32 -> Ws[n][k] bf16
        #pragma unroll
        for (int i = 0; i < (BK * BN) / 1024; ++i) {
            const int idx = tid * 4 + i * 1024;
            const int kk = idx / BN, n = idx % BN;
            float4 v = *(const float4*)(W + (size_t)(k0 + kk) * N + n0 + n);
            Ws[(n + 0) * STR + kk] = f2bf(v.x);
            Ws[(n + 1) * STR + kk] = f2bf(v.y);
            Ws[(n + 2) * STR + kk] = f2bf(v.z);
            Ws[(n + 3) * STR + kk] = f2bf(v.w);
        }
        __syncthreads();

        #pragma unroll
        for (int ks = 0; ks < BK / 32; ++ks) {
            bfrag8 af[4], bfr[NT];
            #pragma unroll
            for (int mt = 0; mt < 4; ++mt)
                af[mt] = *(const bfrag8*)(As + (wm * 64 + mt * 16 + lm) * STR + ks * 32 + quad * 8);
            #pragma unroll
            for (int nt = 0; nt < NT; ++nt)
                bfr[nt] = *(const bfrag8*)(Ws + (wn * (BN / 2) + nt * 16 + lm) * STR + ks * 32 + quad * 8);
            #pragma unroll
            for (int mt = 0; mt < 4; ++mt)
                #pragma unroll
                for (int nt = 0; nt < NT; ++nt)
                    acc[mt][nt] = __builtin_amdgcn_mfma_f32_16x16x32_bf16(
                        af[mt], bfr[nt], acc[mt][nt], 0, 0, 0);
        }
        __syncthreads();
    }

    // ---- epilogue: bias + relu, bf16 store
    // C/D layout (m89/m91-verified): col = lane&15, row = quad*4 + reg
    #pragma unroll
    for (int nt = 0; nt < NT; ++nt) {
        const int col = n0 + wn * (BN / 2) + nt * 16 + lm;
        const float bv = bias[col];
        #pragma unroll
        for (int mt = 0; mt < 4; ++mt) {
            #pragma unroll
            for (int i = 0; i < 4; ++i) {
                const int row = m0 + wm * 64 + mt * 16 + quad * 4 + i;
                float v = acc[mt][nt][i] + bv;
                v = fmaxf(v, 0.f);
                C[(size_t)row * N + col] = f2bf(v);
            }
        }
    }
}

// ---------------------------------------------------------------------------
// Kernel 5: out[r] = H3[r,:] . Wp + bp   (H3: [B,64] bf16)
// Row = 64 bf16 = 8 uint4 loads; each uint4 holds 8 bf16 (lo/hi per word).
// ---------------------------------------------------------------------------
__global__ __launch_bounds__(256) void final_dot(
    const unsigned short* __restrict__ H, const float* __restrict__ Wp,
    const float* __restrict__ bp, float* __restrict__ out)
{
    __shared__ float w[64];
    const int tid = threadIdx.x;
    if (tid < 64) w[tid] = Wp[tid];
    __syncthreads();

    const int r = blockIdx.x * 256 + tid;
    const uint4* h = (const uint4*)(H + (size_t)r * 64);   // 8 x uint4 per row
    float acc = 0.f;
    #pragma unroll
    for (int c = 0; c < 8; ++c) {
        uint4 q = h[c];
        unsigned vals[4] = { q.x, q.y, q.z, q.w };
        #pragma unroll
        for (int e = 0; e < 4; ++e) {
            acc = fmaf(bf2f(vals[e] & 0xFFFFu), w[c * 8 + 2 * e + 0], acc);
            acc = fmaf(bf2f(vals[e] >> 16),     w[c * 8 + 2 * e + 1], acc);
        }
    }
    out[r] = acc + bp[0];
}

// ---------------------------------------------------------------------------
extern "C" void kernel_launch(void* const* d_in, const int* in_sizes, int n_in,
                              void* d_out, int out_size, void* d_ws, size_t ws_size,
                              hipStream_t stream) {
    (void)in_sizes; (void)n_in; (void)out_size; (void)ws_size;

    const int*   user = (const int*)d_in[0];
    const int*   item = (const int*)d_in[1];
    const int*   pk   = (const int*)d_in[2];
    const int*   tk   = (const int*)d_in[3];
    const int*   ik   = (const int*)d_in[4];
    const int*   vp   = (const int*)d_in[5];
    const int*   vt   = (const int*)d_in[6];
    const int*   vi   = (const int*)d_in[7];
    const float* eu   = (const float*)d_in[8];
    const float* ei   = (const float*)d_in[9];
    const float* ek   = (const float*)d_in[10];
    const float* W1   = (const float*)d_in[11];
    const float* b1   = (const float*)d_in[12];
    const float* W2   = (const float*)d_in[13];
    const float* b2   = (const float*)d_in[14];
    const float* W3   = (const float*)d_in[15];
    const float* b3   = (const float*)d_in[16];
    const float* Wp   = (const float*)d_in[17];
    const float* bp   = (const float*)d_in[18];
    float* out = (float*)d_out;

    // ws layout (all bf16): X[B,448] | H1[B,256] | H3[B,64]; H2 aliases X.
    unsigned short* X  = (unsigned short*)d_ws;
    unsigned short* H1 = X + (size_t)B_ROWS * 448;
    unsigned short* H2 = X;                                  // alias X
    unsigned short* H3 = H1 + (size_t)B_ROWS * 256;

    gather_concat<<<B_ROWS / 4, 256, 0, stream>>>(
        user, item, pk, tk, ik, vp, vt, vi, eu, ei, ek, X);

    gemm_mfma<448, 256, 128>
        <<<dim3(2, B_ROWS / 128), 256, 0, stream>>>(X, W1, b1, H1);

    gemm_mfma<256, 128, 128>
        <<<dim3(1, B_ROWS / 128), 256, 0, stream>>>(H1, W2, b2, H2);

    gemm_mfma<128, 64, 64>
        <<<dim3(1, B_ROWS / 128), 256, 0, stream>>>(H2, W3, b3, H3);

    final_dot<<<B_ROWS / 256, 256, 0, stream>>>(H3, Wp, bp, out);
}

// Round 5
// 252.128 us; speedup vs baseline: 2.2964x; 1.2849x over previous
//
#include <hip/hip_runtime.h>
#include <hip/hip_bf16.h>

#define B_ROWS 65536
#define KNUM 20

typedef short  bfrag8 __attribute__((ext_vector_type(8)));  // 8 bf16 (4 VGPRs)
typedef float  facc4  __attribute__((ext_vector_type(4)));  // 4 fp32 acc

__device__ __forceinline__ unsigned short f2bf(float f) {
    union { float f; unsigned u; } x; x.f = f;
    unsigned r = (x.u + 0x7FFFu + ((x.u >> 16) & 1u)) >> 16;   // RNE
    return (unsigned short)r;
}
__device__ __forceinline__ float bf2f(unsigned s) {
    union { unsigned u; float f; } x; x.u = s << 16; return x.f;
}

// ---------------------------------------------------------------------------
// Prepack (runs every call): weights -> bf16, transposed to [N][K] row-major
// (the B-fragment-friendly layout verified in round 3), emb_k -> bf16.
//   WT1: 114688 ush | WT2: 32768 | WT3: 8192 | ekb: 320000
// ---------------------------------------------------------------------------
__global__ __launch_bounds__(256) void prepack(
    const float* __restrict__ W1, const float* __restrict__ W2,
    const float* __restrict__ W3, const float* __restrict__ ek,
    unsigned short* __restrict__ WT1, unsigned short* __restrict__ WT2,
    unsigned short* __restrict__ WT3, unsigned short* __restrict__ ekb)
{
    const int i = blockIdx.x * 256 + threadIdx.x;
    if (i < 114688) {                 // WT1[n*448+k] = bf16(W1[k*256+n])
        const int n = i / 448, k = i % 448;
        WT1[i] = f2bf(W1[k * 256 + n]);
    } else if (i < 147456) {          // WT2[n*256+k] = bf16(W2[k*128+n])
        const int j = i - 114688;
        const int n = j >> 8, k = j & 255;
        WT2[j] = f2bf(W2[k * 128 + n]);
    } else if (i < 155648) {          // WT3[n*128+k] = bf16(W3[k*64+n])
        const int j = i - 147456;
        const int n = j >> 7, k = j & 127;
        WT3[j] = f2bf(W3[k * 64 + n]);
    } else if (i < 475648) {          // ekb = bf16(ek), flat
        const int j = i - 155648;
        ekb[j] = f2bf(ek[j]);
    }
}

// ---------------------------------------------------------------------------
// Fused KDMLP: gather -> GEMM1 -> GEMM2 -> GEMM3 -> dot, one block = 64 rows.
// 512 threads = 8 waves. Intermediates live only in LDS:
//   [0, 58368)  : Xs[64][456] ushort (gather + GEMM1 A-source)
//                 then H1s[64][264] at 0 (..33792) and H2s[64][136] at 33792
//                 (..51200) — both inside the dead Xs region.
//   [58368, 59392): tmp[64][4] float (final reduction)
// Total 59392 B static LDS -> 2 blocks/CU (16 waves/CU).
// B-operands are read straight from prepacked WT* in L2 (16 rows x 64 B
// contiguous per wave-load -> full-line fetches, no LDS staging, no barriers
// in the K-loops).
// ---------------------------------------------------------------------------
__global__ __launch_bounds__(512, 4) void kdmlp_fused(
    const int* __restrict__ user, const int* __restrict__ item,
    const int* __restrict__ pk, const int* __restrict__ tk, const int* __restrict__ ik,
    const int* __restrict__ vp, const int* __restrict__ vt, const int* __restrict__ vi,
    const float* __restrict__ eu, const float* __restrict__ ei,
    const unsigned short* __restrict__ WT1, const unsigned short* __restrict__ WT2,
    const unsigned short* __restrict__ WT3, const unsigned short* __restrict__ ekb,
    const float* __restrict__ b1, const float* __restrict__ b2,
    const float* __restrict__ b3, const float* __restrict__ Wp,
    const float* __restrict__ bp, float* __restrict__ out)
{
    __shared__ char smem[59392];
    unsigned short* Xs  = (unsigned short*)smem;            // stride 456
    unsigned short* H1s = (unsigned short*)smem;            // stride 264
    unsigned short* H2s = (unsigned short*)(smem + 33792);  // stride 136
    float (*tmp)[4]     = (float(*)[4])(smem + 58368);

    const int tid  = threadIdx.x;
    const int lane = tid & 63;
    const int wid  = tid >> 6;          // 0..7
    const int lm   = lane & 15;
    const int quad = lane >> 4;
    const int m0   = blockIdx.x * 64;

    // ================= phase 0: gather + masked means -> Xs =================
    for (int lr = 0; lr < 8; ++lr) {
        const int rl = wid * 8 + lr;    // local row 0..63
        const int r  = m0 + rl;
        const int u   = user[r];
        const int itm = item[r];
        float2 a = *(const float2*)(eu + (size_t)u   * 128 + 2 * lane);
        float2 b = *(const float2*)(ei + (size_t)itm * 128 + 2 * lane);
        ushort2 pa; pa.x = f2bf(a.x); pa.y = f2bf(a.y);
        ushort2 pb; pb.x = f2bf(b.x); pb.y = f2bf(b.y);
        *(ushort2*)(Xs + rl * 456 + 2 * lane)       = pa;
        *(ushort2*)(Xs + rl * 456 + 128 + 2 * lane) = pb;

        const int* idxs[3] = { pk + r * KNUM, tk + r * KNUM, ik + r * KNUM };
        const int  vals[3] = { vp[r], vt[r], vi[r] };
        #pragma unroll
        for (int s = 0; s < 3; ++s) {
            const int valid = vals[s];
            float acc = 0.f;
            #pragma unroll
            for (int j = 0; j < KNUM; ++j) {
                const int kk = idxs[s][j];                      // in-bounds always
                const float v = bf2f(ekb[(size_t)kk * 64 + lane]);  // 128B, L2-hot
                acc += (j < valid) ? v : 0.f;
            }
            const float mean = (valid > 0) ? acc / (float)valid : 0.f;
            Xs[rl * 456 + 256 + s * 64 + lane] = f2bf(mean);
        }
    }
    __syncthreads();

    // ================= GEMM1: [64,448] @ W1 -> H1 [64,256] ==================
    // wave wid covers cols wid*32..+32 (nt 0..1), all 64 rows (mt 0..3).
    facc4 acc1[4][2];
    #pragma unroll
    for (int mt = 0; mt < 4; ++mt)
        #pragma unroll
        for (int nt = 0; nt < 2; ++nt)
            acc1[mt][nt] = (facc4){0.f, 0.f, 0.f, 0.f};

    #pragma unroll
    for (int ks = 0; ks < 14; ++ks) {           // K = 448 = 14 * 32
        bfrag8 af[4], bfv[2];
        #pragma unroll
        for (int mt = 0; mt < 4; ++mt)
            af[mt] = *(const bfrag8*)(Xs + (mt * 16 + lm) * 456 + ks * 32 + quad * 8);
        #pragma unroll
        for (int nt = 0; nt < 2; ++nt)
            bfv[nt] = *(const bfrag8*)(WT1 + (size_t)(wid * 32 + nt * 16 + lm) * 448
                                           + ks * 32 + quad * 8);
        #pragma unroll
        for (int mt = 0; mt < 4; ++mt)
            #pragma unroll
            for (int nt = 0; nt < 2; ++nt)
                acc1[mt][nt] = __builtin_amdgcn_mfma_f32_16x16x32_bf16(
                    af[mt], bfv[nt], acc1[mt][nt], 0, 0, 0);
    }
    __syncthreads();                            // all Xs reads done

    // epilogue 1 -> H1s (C/D: col=lm-based, row=quad*4+reg; round-3 verified)
    #pragma unroll
    for (int nt = 0; nt < 2; ++nt) {
        const int col = wid * 32 + nt * 16 + lm;
        const float bias = b1[col];
        #pragma unroll
        for (int mt = 0; mt < 4; ++mt)
            #pragma unroll
            for (int i = 0; i < 4; ++i) {
                const int row = mt * 16 + quad * 4 + i;
                H1s[row * 264 + col] = f2bf(fmaxf(acc1[mt][nt][i] + bias, 0.f));
            }
    }
    __syncthreads();

    // ================= GEMM2: [64,256] @ W2 -> H2 [64,128] ==================
    facc4 acc2[4];
    #pragma unroll
    for (int mt = 0; mt < 4; ++mt) acc2[mt] = (facc4){0.f, 0.f, 0.f, 0.f};

    const int col2 = wid * 16 + lm;
    #pragma unroll
    for (int ks = 0; ks < 8; ++ks) {            // K = 256 = 8 * 32
        bfrag8 af[4];
        #pragma unroll
        for (int mt = 0; mt < 4; ++mt)
            af[mt] = *(const bfrag8*)(H1s + (mt * 16 + lm) * 264 + ks * 32 + quad * 8);
        bfrag8 bfv = *(const bfrag8*)(WT2 + (size_t)col2 * 256 + ks * 32 + quad * 8);
        #pragma unroll
        for (int mt = 0; mt < 4; ++mt)
            acc2[mt] = __builtin_amdgcn_mfma_f32_16x16x32_bf16(af[mt], bfv, acc2[mt], 0, 0, 0);
    }
    {   // epilogue 2 -> H2s (disjoint LDS region; no barrier needed before)
        const float bias = b2[col2];
        #pragma unroll
        for (int mt = 0; mt < 4; ++mt)
            #pragma unroll
            for (int i = 0; i < 4; ++i) {
                const int row = mt * 16 + quad * 4 + i;
                H2s[row * 136 + col2] = f2bf(fmaxf(acc2[mt][i] + bias, 0.f));
            }
    }
    __syncthreads();

    // ========= GEMM3: [64,128] @ W3 -> relu -> dot Wp, fused reduce =========
    if (wid < 4) {
        facc4 acc3[4];
        #pragma unroll
        for (int mt = 0; mt < 4; ++mt) acc3[mt] = (facc4){0.f, 0.f, 0.f, 0.f};

        const int col3 = wid * 16 + lm;
        #pragma unroll
        for (int ks = 0; ks < 4; ++ks) {        // K = 128 = 4 * 32
            bfrag8 af[4];
            #pragma unroll
            for (int mt = 0; mt < 4; ++mt)
                af[mt] = *(const bfrag8*)(H2s + (mt * 16 + lm) * 136 + ks * 32 + quad * 8);
            bfrag8 bfv = *(const bfrag8*)(WT3 + (size_t)col3 * 128 + ks * 32 + quad * 8);
            #pragma unroll
            for (int mt = 0; mt < 4; ++mt)
                acc3[mt] = __builtin_amdgcn_mfma_f32_16x16x32_bf16(af[mt], bfv, acc3[mt], 0, 0, 0);
        }
        const float bias = b3[col3];
        const float wpv  = Wp[col3];
        #pragma unroll
        for (int mt = 0; mt < 4; ++mt)
            #pragma unroll
            for (int i = 0; i < 4; ++i) {
                float p = fmaxf(acc3[mt][i] + bias, 0.f) * wpv;
                p += __shfl_xor(p, 1);
                p += __shfl_xor(p, 2);
                p += __shfl_xor(p, 4);
                p += __shfl_xor(p, 8);          // sum over 16 cols of this quad
                if (lm == 0) tmp[mt * 16 + quad * 4 + i][wid] = p;
            }
    }
    __syncthreads();

    if (tid < 64)
        out[m0 + tid] = tmp[tid][0] + tmp[tid][1] + tmp[tid][2] + tmp[tid][3] + bp[0];
}

// ---------------------------------------------------------------------------
extern "C" void kernel_launch(void* const* d_in, const int* in_sizes, int n_in,
                              void* d_out, int out_size, void* d_ws, size_t ws_size,
                              hipStream_t stream) {
    (void)in_sizes; (void)n_in; (void)out_size; (void)ws_size;

    const int*   user = (const int*)d_in[0];
    const int*   item = (const int*)d_in[1];
    const int*   pk   = (const int*)d_in[2];
    const int*   tk   = (const int*)d_in[3];
    const int*   ik   = (const int*)d_in[4];
    const int*   vp   = (const int*)d_in[5];
    const int*   vt   = (const int*)d_in[6];
    const int*   vi   = (const int*)d_in[7];
    const float* eu   = (const float*)d_in[8];
    const float* ei   = (const float*)d_in[9];
    const float* ek   = (const float*)d_in[10];
    const float* W1   = (const float*)d_in[11];
    const float* b1   = (const float*)d_in[12];
    const float* W2   = (const float*)d_in[13];
    const float* b2   = (const float*)d_in[14];
    const float* W3   = (const float*)d_in[15];
    const float* b3   = (const float*)d_in[16];
    const float* Wp   = (const float*)d_in[17];
    const float* bp   = (const float*)d_in[18];
    float* out = (float*)d_out;

    // ws: prepacked bf16 weights + emb_k (~951 KB)
    unsigned short* WT1 = (unsigned short*)d_ws;
    unsigned short* WT2 = WT1 + 114688;
    unsigned short* WT3 = WT2 + 32768;
    unsigned short* ekb = WT3 + 8192;

    prepack<<<1858, 256, 0, stream>>>(W1, W2, W3, ek, WT1, WT2, WT3, ekb);

    kdmlp_fused<<<B_ROWS / 64, 512, 0, stream>>>(
        user, item, pk, tk, ik, vp, vt, vi, eu, ei,
        WT1, WT2, WT3, ekb, b1, b2, b3, Wp, bp, out);
}